// Round 28
// baseline (106.134 us; speedup 1.0000x reference)
//
#include <hip/hip_runtime.h>
#include <math.h>

constexpr int T  = 2048;
constexpr int Dm = 1024;
constexpr int NH = 16;
constexpr int DH = 64;
constexpr int KS = 2;              // split-K ways (flash); KS=4 regressed r19

typedef unsigned short u16;
typedef _Float16 f16;
typedef f16 f16x8 __attribute__((ext_vector_type(8)));
typedef __fp16 fp16x2 __attribute__((ext_vector_type(2)));
typedef float f32x4 __attribute__((ext_vector_type(4)));

#define MFMAH(a, b, c) __builtin_amdgcn_mfma_f32_16x16x32_f16((a), (b), (c), 0, 0, 0)

__device__ __forceinline__ float h2f(u16 h) {
    union { u16 u; f16 h; } v; v.u = h; return (float)v.h;
}
__device__ __forceinline__ u16 f2h(float f) {
    union { u16 u; f16 h; } v; v.h = (f16)f; return v.u;
}

// ---------------------------------------------------------------------------
// prep: fused xconv + wtrans + wout_conv + AP build (invfreq inlined).
// ---------------------------------------------------------------------------
__global__ __launch_bounds__(256) void prep_kernel(
    const float* __restrict__ x,
    const float* __restrict__ Wq, const float* __restrict__ Wk,
    const float* __restrict__ Wv, const float* __restrict__ Wout,
    u16* __restrict__ xh, u16* __restrict__ Wt,
    u16* __restrict__ Wb, u16* __restrict__ ap)
{
    __shared__ float Ls[64][65];
    const int blk = blockIdx.x, tid = threadIdx.x;

    if (blk < 2048) {                       // x fp32 -> fp16
        size_t i = ((size_t)blk * 256 + tid) * 4;
        float4 v = *(const float4*)(x + i);
        ushort4 hv;
        hv.x = f2h(v.x); hv.y = f2h(v.y); hv.z = f2h(v.z); hv.w = f2h(v.w);
        *(ushort4*)(xh + i) = hv;
    } else if (blk < 2816) {                // W[h][k][n] -> Wt[(z,h)][n][k]
        int rel = blk - 2048;
        int kc = (rel & 15) * 64, h = (rel >> 4) & 15, z = rel >> 8;
        const float* W = (z == 0) ? Wq : (z == 1) ? Wk : Wv;
        #pragma unroll
        for (int it = 0; it < 4; ++it) {
            int idx = it * 256 + tid;
            int kl = idx >> 4, n4 = (idx & 15) * 4;
            float4 v = *(const float4*)(W + ((size_t)h * Dm + kc + kl) * DH + n4);
            Ls[n4+0][kl] = v.x; Ls[n4+1][kl] = v.y;
            Ls[n4+2][kl] = v.z; Ls[n4+3][kl] = v.w;
        }
        __syncthreads();
        const int n = tid >> 2, k16 = (tid & 3) * 16;
        union { u16 u[16]; int4 v[2]; } tmp;
        #pragma unroll
        for (int j = 0; j < 16; ++j) tmp.u[j] = f2h(Ls[n][k16 + j]);
        u16* dst = Wt + (((size_t)z * NH + h) * DH + n) * Dm + kc + k16;
        *(int4*)(dst)     = tmp.v[0];
        *(int4*)(dst + 8) = tmp.v[1];
    } else if (blk < 3840) {                // Wout fp32 -> fp16
        int rel = blk - 2816;
        size_t i = ((size_t)rel * 256 + tid) * 4;
        float4 v = *(const float4*)(Wout + i);
        ushort4 hv;
        hv.x = f2h(v.x); hv.y = f2h(v.y); hv.z = f2h(v.z); hv.w = f2h(v.w);
        *(ushort4*)(Wb + i) = hv;
    } else {                                // AP[t][s], invfreq inline
        int rel = blk - 3840;
        int p = (rel & 3) * 256 + tid;      // s-pair index
        int t = rel >> 2;
        int s = p * 2;
        float f = exp2f(-(float)s * 0.01297671165f);
        float sn, cs;
        __sincosf((float)t * f, &sn, &cs);
        unsigned int packed = (unsigned int)f2h(sn) | ((unsigned int)f2h(cs) << 16);
        *(unsigned int*)(ap + (size_t)t * T + s) = packed;
    }
}

// ---------------------------------------------------------------------------
// Fused QKV projection, fp16 MFMA + swizzled LDS staging (r18-validated).
// ---------------------------------------------------------------------------
__global__ __launch_bounds__(256) void proj_mfma(
    const u16* __restrict__ xh, const u16* __restrict__ Wt,
    u16* __restrict__ Qh, u16* __restrict__ Kh, u16* __restrict__ Vt)
{
    __shared__ u16 Xs[4096];
    __shared__ u16 WsQ[4096];
    __shared__ u16 WsK[4096];
    __shared__ u16 WsV[4096];

    const int t0 = blockIdx.x * 64, h = blockIdx.y;
    const int tid = threadIdx.x, w = tid >> 6, lane = tid & 63;
    const int b = lane & 15, a = lane >> 4;

    const int srow = tid >> 2, sc16 = (tid & 3) * 16;
    const int swz = (srow & 7) << 4;
    const int sb0 = (srow * 128 + sc16 * 2) ^ swz;
    const int sb1 = (srow * 128 + sc16 * 2 + 16) ^ swz;

    const u16* WQb = Wt + ((size_t)0 * NH + h) * DH * Dm;
    const u16* WKb = Wt + ((size_t)1 * NH + h) * DH * Dm;
    const u16* WVb = Wt + ((size_t)2 * NH + h) * DH * Dm;

    f32x4 aq[4], ak[4], av[4];
    #pragma unroll
    for (int ct = 0; ct < 4; ++ct) {
        aq[ct] = (f32x4){0.f, 0.f, 0.f, 0.f};
        ak[ct] = (f32x4){0.f, 0.f, 0.f, 0.f};
        av[ct] = (f32x4){0.f, 0.f, 0.f, 0.f};
    }

    for (int kc = 0; kc < Dm; kc += 64) {
        __syncthreads();
        {
            const u16* gx  = xh  + (size_t)(t0 + srow) * Dm + kc + sc16;
            const u16* gwq = WQb + (size_t)srow * Dm + kc + sc16;
            const u16* gwk = WKb + (size_t)srow * Dm + kc + sc16;
            const u16* gwv = WVb + (size_t)srow * Dm + kc + sc16;
            *(int4*)((char*)Xs  + sb0) = *(const int4*)gx;
            *(int4*)((char*)Xs  + sb1) = *(const int4*)(gx + 8);
            *(int4*)((char*)WsQ + sb0) = *(const int4*)gwq;
            *(int4*)((char*)WsQ + sb1) = *(const int4*)(gwq + 8);
            *(int4*)((char*)WsK + sb0) = *(const int4*)gwk;
            *(int4*)((char*)WsK + sb1) = *(const int4*)(gwk + 8);
            *(int4*)((char*)WsV + sb0) = *(const int4*)gwv;
            *(int4*)((char*)WsV + sb1) = *(const int4*)(gwv + 8);
        }
        __syncthreads();

        f16x8 ax[2];
        #pragma unroll
        for (int ks = 0; ks < 2; ++ks) {
            int row = 16 * w + b;
            int byt = (row * 128 + ks * 64 + a * 16) ^ ((row & 7) << 4);
            ax[ks] = *(const f16x8*)((const char*)Xs + byt);
        }
        __builtin_amdgcn_s_setprio(1);
        #pragma unroll
        for (int ct = 0; ct < 4; ++ct) {
            #pragma unroll
            for (int ks = 0; ks < 2; ++ks) {
                int row = 16 * ct + b;
                int byt = (row * 128 + ks * 64 + a * 16) ^ ((row & 7) << 4);
                f16x8 bq = *(const f16x8*)((const char*)WsQ + byt);
                f16x8 bk = *(const f16x8*)((const char*)WsK + byt);
                f16x8 bv = *(const f16x8*)((const char*)WsV + byt);
                aq[ct] = MFMAH(ax[ks], bq, aq[ct]);
                ak[ct] = MFMAH(ax[ks], bk, ak[ct]);
                av[ct] = MFMAH(ax[ks], bv, av[ct]);
            }
        }
        __builtin_amdgcn_s_setprio(0);
    }

    const size_t base = (size_t)h * T * DH;
    #pragma unroll
    for (int ct = 0; ct < 4; ++ct) {
        #pragma unroll
        for (int r = 0; r < 4; ++r) {
            int t = t0 + 16 * w + a * 4 + r;
            size_t off = base + (size_t)t * DH + 16 * ct + b;
            Qh[off] = f2h(aq[ct][r]);
            Kh[off] = f2h(ak[ct][r]);
            Vt[((size_t)h * DH + 16 * ct + b) * T + t] = f2h(av[ct][r]);
        }
    }
}

// ---------------------------------------------------------------------------
// fp16 MFMA flash attention, split-K (KS=2), swapped operands, QBLK=128:
// 8-wave (512-thr) blocks; per K/V tile staged, 2x q-rows consume it ->
// staging traffic, barriers, stage-drain per s-element all halve. Row
// layouts (128B + XOR swizzle) byte-identical to the r18-validated form.
// ---------------------------------------------------------------------------
__global__ __launch_bounds__(512) void flash_mfma_split(
    const u16* __restrict__ Qh, const u16* __restrict__ Kh,
    const u16* __restrict__ Vt, const u16* __restrict__ AP,
    u16* __restrict__ Opart, float2* __restrict__ ml)
{
    __shared__ u16 Ks[4096];
    __shared__ u16 Vs[4096];
    __shared__ u16 Ps[8][1024];

    const int h = blockIdx.y, t0 = blockIdx.x * 128;
    const int split = blockIdx.z;
    const int s_begin = split * (T / KS), s_end = s_begin + T / KS;
    const int tid = threadIdx.x, w = tid >> 6, lane = tid & 63;
    const int b = lane & 15, a = lane >> 4;

    const size_t hTD = (size_t)h * T * DH;
    const int trow = t0 + 16 * w + b;          // this lane's q-row (128 span)

    const size_t qoff = hTD + (size_t)trow * DH + a * 8;
    f16x8 qf[2];
    qf[0] = *(const f16x8*)(Qh + qoff);
    qf[1] = *(const f16x8*)(Qh + qoff + 32);

    f32x4 oacc[4];
    float m_run = -INFINITY, l_run = 0.f;
    #pragma unroll
    for (int i = 0; i < 4; ++i) oacc[i] = (f32x4){0.f, 0.f, 0.f, 0.f};

    // staging: threads 0..255 stage K, 256..511 stage V (same pattern each)
    const int stid = tid & 255;
    const int srow = stid >> 2, sc16 = (stid & 3) * 16;
    const int swz = (srow & 7) << 4;
    const int sb0 = (srow * 128 + sc16 * 2) ^ swz;
    const int sb1 = (srow * 128 + sc16 * 2 + 16) ^ swz;
    u16* stbuf = (tid < 256) ? Ks : Vs;

    const u16* aprow = AP + (size_t)trow * T;

    for (int s0 = s_begin; s0 < s_end; s0 += 64) {
        __syncthreads();
        {
            const u16* g = (tid < 256)
                ? Kh + hTD + (size_t)(s0 + srow) * DH + sc16
                : Vt + hTD + (size_t)srow * T + s0 + sc16;
            *(int4*)((char*)stbuf + sb0) = *(const int4*)g;
            *(int4*)((char*)stbuf + sb1) = *(const int4*)(g + 8);
        }
        __syncthreads();

        ushort4 ap4[4];
        #pragma unroll
        for (int ct = 0; ct < 4; ++ct)
            ap4[ct] = *(const ushort4*)(aprow + s0 + 16 * ct + 4 * a);

        f32x4 acc[4];
        #pragma unroll
        for (int ct = 0; ct < 4; ++ct) acc[ct] = (f32x4){0.f, 0.f, 0.f, 0.f};
        #pragma unroll
        for (int ct = 0; ct < 4; ++ct) {
            #pragma unroll
            for (int ks = 0; ks < 2; ++ks) {
                int row = 16 * ct + b;
                int byt = (row * 128 + ks * 64 + a * 16) ^ ((row & 7) << 4);
                f16x8 kf = *(const f16x8*)((const char*)Ks + byt);
                acc[ct] = MFMAH(kf, qf[ks], acc[ct]);   // swapped
            }
        }

        #pragma unroll
        for (int ct = 0; ct < 4; ++ct) {
            const u16* apu = (const u16*)&ap4[ct];
            #pragma unroll
            for (int r = 0; r < 4; ++r)
                acc[ct][r] += h2f(apu[r]);
        }

        float mx = acc[0][0];
        #pragma unroll
        for (int ct = 0; ct < 4; ++ct)
            #pragma unroll
            for (int r = 0; r < 4; ++r) mx = fmaxf(mx, acc[ct][r]);
        mx = fmaxf(mx, __shfl_xor(mx, 16));
        mx = fmaxf(mx, __shfl_xor(mx, 32));

        float mnew  = fmaxf(m_run, mx);
        float alpha = __expf(m_run - mnew);
        float rs = 0.f;
        #pragma unroll
        for (int ct = 0; ct < 4; ++ct) {
            #pragma unroll
            for (int r = 0; r < 4; ++r) {
                float p = __expf(acc[ct][r] - mnew);
                acc[ct][r] = p;
                rs += p;
            }
        }
        rs += __shfl_xor(rs, 16);
        rs += __shfl_xor(rs, 32);
        l_run = l_run * alpha + rs;
        m_run = mnew;
        #pragma unroll
        for (int dt = 0; dt < 4; ++dt) {
            oacc[dt][0] *= alpha; oacc[dt][1] *= alpha;
            oacc[dt][2] *= alpha; oacc[dt][3] *= alpha;
        }

        #pragma unroll
        for (int ct = 0; ct < 4; ++ct) {
            union { fp16x2 h[2]; int2 i2; } u;
            u.h[0] = __builtin_amdgcn_cvt_pkrtz(acc[ct][0], acc[ct][1]);
            u.h[1] = __builtin_amdgcn_cvt_pkrtz(acc[ct][2], acc[ct][3]);
            int byt = (b * 128 + ct * 32 + a * 8) ^ ((b & 7) << 4);
            *(int2*)((char*)Ps[w] + byt) = u.i2;
        }

        f16x8 pa[2];
        #pragma unroll
        for (int ks = 0; ks < 2; ++ks) {
            int byt = (b * 128 + ks * 64 + a * 16) ^ ((b & 7) << 4);
            pa[ks] = *(const f16x8*)((const char*)Ps[w] + byt);
        }
        #pragma unroll
        for (int dt = 0; dt < 4; ++dt) {
            #pragma unroll
            for (int ks = 0; ks < 2; ++ks) {
                int row = 16 * dt + b;
                int byt = (row * 128 + ks * 64 + a * 16) ^ ((row & 7) << 4);
                f16x8 vf = *(const f16x8*)((const char*)Vs + byt);
                oacc[dt] = MFMAH(vf, pa[ks], oacc[dt]);   // swapped
            }
        }
    }

    const size_t pbase = ((size_t)split * NH + h) * T;
    #pragma unroll
    for (int dt = 0; dt < 4; ++dt) {
        ushort4 ov;
        ov.x = f2h(oacc[dt][0]); ov.y = f2h(oacc[dt][1]);
        ov.z = f2h(oacc[dt][2]); ov.w = f2h(oacc[dt][3]);
        *(ushort4*)(Opart + (pbase + trow) * DH + 16 * dt + 4 * a) = ov;
    }
    if (a == 0) ml[pbase + trow] = make_float2(m_run, l_run);
}

// ---------------------------------------------------------------------------
// Combine KS split partials; stores (m*, 1/L) for head 15 softmax fusion.
// ---------------------------------------------------------------------------
__global__ __launch_bounds__(256) void flash_combine(
    const u16* __restrict__ Opart, const float2* __restrict__ ml,
    u16* __restrict__ Ych, float2* __restrict__ mlfinal)
{
    int idx = blockIdx.x * 256 + threadIdx.x;
    int h = idx >> 14;
    int rem = idx & 16383;
    int t = rem >> 3;
    int d8 = (rem & 7) * 8;

    float2 mls[KS];
    size_t rr[KS];
    float m = -INFINITY;
    #pragma unroll
    for (int s = 0; s < KS; ++s) {
        rr[s] = ((size_t)s * NH + h) * T + t;
        mls[s] = ml[rr[s]];
        m = fmaxf(m, mls[s].x);
    }
    float wgt[KS], L = 0.f;
    #pragma unroll
    for (int s = 0; s < KS; ++s) {
        wgt[s] = __expf(mls[s].x - m);
        L += wgt[s] * mls[s].y;
    }
    float inv = 1.f / L;
    if (h == NH - 1 && d8 == 0) mlfinal[t] = make_float2(m, inv);

    float o[8] = {};
    #pragma unroll
    for (int s = 0; s < KS; ++s) {
        union { u16 u[8]; int4 v; } ov;
        ov.v = *(const int4*)(Opart + rr[s] * DH + d8);
        float ws = wgt[s] * inv;
        #pragma unroll
        for (int j = 0; j < 8; ++j) o[j] += h2f(ov.u[j]) * ws;
    }
    union { u16 u[8]; int4 v; } yo;
    #pragma unroll
    for (int j = 0; j < 8; ++j) yo.u[j] = f2h(o[j]);
    *(int4*)(Ych + (size_t)t * Dm + h * DH + d8) = yo.v;
}

// ---------------------------------------------------------------------------
// tail: fused gemm_out (blocks [0,512)) + head-15 score map ([512,1536)).
// ---------------------------------------------------------------------------
__global__ __launch_bounds__(256) void tail_kernel(
    const u16* __restrict__ Qh, const u16* __restrict__ Kh,
    const u16* __restrict__ AP, const float2* __restrict__ mlf,
    const u16* __restrict__ Ych, const u16* __restrict__ Wb,
    float* __restrict__ S, float* __restrict__ y)
{
    __shared__ u16 lds[8192];
    const int blk = blockIdx.x, tid = threadIdx.x;
    const int w = tid >> 6, lane = tid & 63;
    const int b = lane & 15, a = lane >> 4;
    const int srow = tid >> 2, sc16 = (tid & 3) * 16;
    const int swz = (srow & 7) << 4;
    const int sb0 = (srow * 128 + sc16 * 2) ^ swz;
    const int sb1 = (srow * 128 + sc16 * 2 + 16) ^ swz;

    if (blk < 512) {
        // ---- gemm_out: y = Ych @ Wb^T ----
        u16* As = lds;
        u16* Bs = lds + 4096;
        const int n0 = (blk & 15) * 64, t0 = (blk >> 4) * 64;

        f32x4 acc[4];
        #pragma unroll
        for (int ct = 0; ct < 4; ++ct) acc[ct] = (f32x4){0.f, 0.f, 0.f, 0.f};

        for (int kc = 0; kc < Dm; kc += 64) {
            __syncthreads();
            {
                const u16* ga = Ych + (size_t)(t0 + srow) * Dm + kc + sc16;
                const u16* gb = Wb  + (size_t)(n0 + srow) * Dm + kc + sc16;
                *(int4*)((char*)As + sb0) = *(const int4*)ga;
                *(int4*)((char*)As + sb1) = *(const int4*)(ga + 8);
                *(int4*)((char*)Bs + sb0) = *(const int4*)gb;
                *(int4*)((char*)Bs + sb1) = *(const int4*)(gb + 8);
            }
            __syncthreads();

            f16x8 af[2];
            #pragma unroll
            for (int ks = 0; ks < 2; ++ks) {
                int row = 16 * w + b;
                int byt = (row * 128 + ks * 64 + a * 16) ^ ((row & 7) << 4);
                af[ks] = *(const f16x8*)((const char*)As + byt);
            }
            __builtin_amdgcn_s_setprio(1);
            #pragma unroll
            for (int ct = 0; ct < 4; ++ct) {
                #pragma unroll
                for (int ks = 0; ks < 2; ++ks) {
                    int row = 16 * ct + b;
                    int byt = (row * 128 + ks * 64 + a * 16) ^ ((row & 7) << 4);
                    f16x8 bw = *(const f16x8*)((const char*)Bs + byt);
                    acc[ct] = MFMAH(af[ks], bw, acc[ct]);
                }
            }
            __builtin_amdgcn_s_setprio(0);
        }

        #pragma unroll
        for (int r = 0; r < 4; ++r) {
            int t = t0 + 16 * w + a * 4 + r;
            #pragma unroll
            for (int ct = 0; ct < 4; ++ct)
                y[(size_t)t * Dm + n0 + 16 * ct + b] = acc[ct][r];
        }
    } else {
        // ---- head-15 score map with fused softmax (swapped operands) ----
        u16* Ks = lds;
        const int rel = blk - 512;
        const int s0 = (rel & 31) * 64, t0 = (rel >> 5) * 64;
        const int h = NH - 1;
        const size_t hTD = (size_t)h * T * DH;
        const int trow = t0 + 16 * w + b;

        {
            const u16* gk = Kh + hTD + (size_t)(s0 + srow) * DH + sc16;
            *(int4*)((char*)Ks + sb0) = *(const int4*)gk;
            *(int4*)((char*)Ks + sb1) = *(const int4*)(gk + 8);
        }

        const size_t qoff = hTD + (size_t)trow * DH + a * 8;
        f16x8 qf[2];
        qf[0] = *(const f16x8*)(Qh + qoff);
        qf[1] = *(const f16x8*)(Qh + qoff + 32);
        __syncthreads();

        ushort4 ap4[4];
        #pragma unroll
        for (int ct = 0; ct < 4; ++ct)
            ap4[ct] = *(const ushort4*)(AP + (size_t)trow * T + s0 + 16 * ct + 4 * a);
        float2 fml = mlf[trow];

        f32x4 acc[4];
        #pragma unroll
        for (int ct = 0; ct < 4; ++ct) acc[ct] = (f32x4){0.f, 0.f, 0.f, 0.f};
        #pragma unroll
        for (int ct = 0; ct < 4; ++ct) {
            #pragma unroll
            for (int ks = 0; ks < 2; ++ks) {
                int row = 16 * ct + b;
                int byt = (row * 128 + ks * 64 + a * 16) ^ ((row & 7) << 4);
                f16x8 kf = *(const f16x8*)((const char*)Ks + byt);
                acc[ct] = MFMAH(kf, qf[ks], acc[ct]);    // swapped
            }
        }

        #pragma unroll
        for (int ct = 0; ct < 4; ++ct) {
            const u16* apu = (const u16*)&ap4[ct];
            float4 o;
            o.x = __expf(acc[ct][0] + h2f(apu[0]) - fml.x) * fml.y;
            o.y = __expf(acc[ct][1] + h2f(apu[1]) - fml.x) * fml.y;
            o.z = __expf(acc[ct][2] + h2f(apu[2]) - fml.x) * fml.y;
            o.w = __expf(acc[ct][3] + h2f(apu[3]) - fml.x) * fml.y;
            *(float4*)(S + (size_t)trow * T + s0 + 16 * ct + 4 * a) = o;
        }
    }
}

// ---------------------------------------------------------------------------
extern "C" void kernel_launch(void* const* d_in, const int* in_sizes, int n_in,
                              void* d_out, int out_size, void* d_ws, size_t ws_size,
                              hipStream_t stream)
{
    const float* x    = (const float*)d_in[0];
    const float* Wq   = (const float*)d_in[1];
    const float* Wk   = (const float*)d_in[2];
    const float* Wv   = (const float*)d_in[3];
    const float* Wout = (const float*)d_in[4];

    float* out      = (float*)d_out;
    float* y_out    = out;
    float* attn_out = out + (long)T * Dm;     // written LAST -> usable scratch

    // ---- workspace layout (32.6 MB; 34.5 MB proven) ----
    char* ws = (char*)d_ws;
    const size_t MB = 1024 * 1024;
    u16* Qh = (u16*)ws;                                // 4 MB
    u16* Kh = (u16*)(ws + 4 * MB);                     // 4 MB
    u16* Vt = (u16*)(ws + 8 * MB);                     // 4 MB
    char* C = ws + 12 * MB;
    u16* xh    = (u16*)C;                              // 4 MB (dead after proj)
    u16* Ych   = (u16*)C;                              // aliases xh (phase 2)
    u16* Wtb   = (u16*)(C + 4 * MB);                   // 6 MB
    u16* Woutb = (u16*)(C + 10 * MB);                  // 2 MB
    u16* APt   = (u16*)(C + 12 * MB);                  // 8 MB ([t][s])
    float2* mlfinal = (float2*)(C + 20 * MB);          // 16 KB
    float2* mlbuf   = (float2*)(C + 20 * MB + 65536);  // 512 KB
    // split-K partial O in d_out attn region (overwritten by tail/score):
    u16* Opart = (u16*)attn_out;                       // KS x 4 MB = 8 MB
    (void)ws_size;

    // 1) fused prep: xconv + wtrans + wout_conv + AP table
    prep_kernel<<<dim3(12032), dim3(256), 0, stream>>>(
        x, Wq, Wk, Wv, Wout, xh, Wtb, Woutb, APt);

    // 2) fused QKV projection
    proj_mfma<<<dim3(T / 64, NH), dim3(256), 0, stream>>>(xh, Wtb, Qh, Kh, Vt);

    // 3) split-K flash attention (QBLK=128, 8-wave blocks)
    flash_mfma_split<<<dim3(T / 128, NH, KS), dim3(512), 0, stream>>>(
        Qh, Kh, Vt, APt, Opart, mlbuf);

    // 4) combine partials -> Ych + (m*,1/L)
    flash_combine<<<dim3(NH * T * 8 / 256), dim3(256), 0, stream>>>(
        Opart, mlbuf, Ych, mlfinal);

    // 5) fused tail: output projection + head-15 attention map
    tail_kernel<<<dim3(1536), dim3(256), 0, stream>>>(
        Qh, Kh, APt, mlfinal, Ych, Woutb, attn_out, y_out);
}

// Round 29
// 104.297 us; speedup vs baseline: 1.0176x; 1.0176x over previous
//
#include <hip/hip_runtime.h>
#include <math.h>

constexpr int T  = 2048;
constexpr int Dm = 1024;
constexpr int NH = 16;
constexpr int DH = 64;
constexpr int KS = 2;              // split-K ways (flash); KS=4 regressed r19

typedef unsigned short u16;
typedef _Float16 f16;
typedef f16 f16x8 __attribute__((ext_vector_type(8)));
typedef __fp16 fp16x2 __attribute__((ext_vector_type(2)));
typedef float f32x4 __attribute__((ext_vector_type(4)));

#define MFMAH(a, b, c) __builtin_amdgcn_mfma_f32_16x16x32_f16((a), (b), (c), 0, 0, 0)

__device__ __forceinline__ float h2f(u16 h) {
    union { u16 u; f16 h; } v; v.u = h; return (float)v.h;
}
__device__ __forceinline__ u16 f2h(float f) {
    union { u16 u; f16 h; } v; v.h = (f16)f; return v.u;
}

// ---------------------------------------------------------------------------
// prep: fused xconv + wtrans + wout_conv + AP build (invfreq inlined).
// ---------------------------------------------------------------------------
__global__ __launch_bounds__(256) void prep_kernel(
    const float* __restrict__ x,
    const float* __restrict__ Wq, const float* __restrict__ Wk,
    const float* __restrict__ Wv, const float* __restrict__ Wout,
    u16* __restrict__ xh, u16* __restrict__ Wt,
    u16* __restrict__ Wb, u16* __restrict__ ap)
{
    __shared__ float Ls[64][65];
    const int blk = blockIdx.x, tid = threadIdx.x;

    if (blk < 2048) {                       // x fp32 -> fp16
        size_t i = ((size_t)blk * 256 + tid) * 4;
        float4 v = *(const float4*)(x + i);
        ushort4 hv;
        hv.x = f2h(v.x); hv.y = f2h(v.y); hv.z = f2h(v.z); hv.w = f2h(v.w);
        *(ushort4*)(xh + i) = hv;
    } else if (blk < 2816) {                // W[h][k][n] -> Wt[(z,h)][n][k]
        int rel = blk - 2048;
        int kc = (rel & 15) * 64, h = (rel >> 4) & 15, z = rel >> 8;
        const float* W = (z == 0) ? Wq : (z == 1) ? Wk : Wv;
        #pragma unroll
        for (int it = 0; it < 4; ++it) {
            int idx = it * 256 + tid;
            int kl = idx >> 4, n4 = (idx & 15) * 4;
            float4 v = *(const float4*)(W + ((size_t)h * Dm + kc + kl) * DH + n4);
            Ls[n4+0][kl] = v.x; Ls[n4+1][kl] = v.y;
            Ls[n4+2][kl] = v.z; Ls[n4+3][kl] = v.w;
        }
        __syncthreads();
        const int n = tid >> 2, k16 = (tid & 3) * 16;
        union { u16 u[16]; int4 v[2]; } tmp;
        #pragma unroll
        for (int j = 0; j < 16; ++j) tmp.u[j] = f2h(Ls[n][k16 + j]);
        u16* dst = Wt + (((size_t)z * NH + h) * DH + n) * Dm + kc + k16;
        *(int4*)(dst)     = tmp.v[0];
        *(int4*)(dst + 8) = tmp.v[1];
    } else if (blk < 3840) {                // Wout fp32 -> fp16
        int rel = blk - 2816;
        size_t i = ((size_t)rel * 256 + tid) * 4;
        float4 v = *(const float4*)(Wout + i);
        ushort4 hv;
        hv.x = f2h(v.x); hv.y = f2h(v.y); hv.z = f2h(v.z); hv.w = f2h(v.w);
        *(ushort4*)(Wb + i) = hv;
    } else {                                // AP[t][s], invfreq inline
        int rel = blk - 3840;
        int p = (rel & 3) * 256 + tid;      // s-pair index
        int t = rel >> 2;
        int s = p * 2;
        // invfreq = 10000^(-s/1024) = exp2(-s * log2(1e4)/1024)
        float f = exp2f(-(float)s * 0.01297671165f);
        float sn, cs;
        __sincosf((float)t * f, &sn, &cs);
        unsigned int packed = (unsigned int)f2h(sn) | ((unsigned int)f2h(cs) << 16);
        *(unsigned int*)(ap + (size_t)t * T + s) = packed;
    }
}

// ---------------------------------------------------------------------------
// Fused QKV projection, fp16 MFMA + swizzled LDS staging (r18-validated).
// ---------------------------------------------------------------------------
__global__ __launch_bounds__(256) void proj_mfma(
    const u16* __restrict__ xh, const u16* __restrict__ Wt,
    u16* __restrict__ Qh, u16* __restrict__ Kh, u16* __restrict__ Vt)
{
    __shared__ u16 Xs[4096];
    __shared__ u16 WsQ[4096];
    __shared__ u16 WsK[4096];
    __shared__ u16 WsV[4096];

    const int t0 = blockIdx.x * 64, h = blockIdx.y;
    const int tid = threadIdx.x, w = tid >> 6, lane = tid & 63;
    const int b = lane & 15, a = lane >> 4;

    const int srow = tid >> 2, sc16 = (tid & 3) * 16;
    const int swz = (srow & 7) << 4;
    const int sb0 = (srow * 128 + sc16 * 2) ^ swz;
    const int sb1 = (srow * 128 + sc16 * 2 + 16) ^ swz;

    const u16* WQb = Wt + ((size_t)0 * NH + h) * DH * Dm;
    const u16* WKb = Wt + ((size_t)1 * NH + h) * DH * Dm;
    const u16* WVb = Wt + ((size_t)2 * NH + h) * DH * Dm;

    f32x4 aq[4], ak[4], av[4];
    #pragma unroll
    for (int ct = 0; ct < 4; ++ct) {
        aq[ct] = (f32x4){0.f, 0.f, 0.f, 0.f};
        ak[ct] = (f32x4){0.f, 0.f, 0.f, 0.f};
        av[ct] = (f32x4){0.f, 0.f, 0.f, 0.f};
    }

    for (int kc = 0; kc < Dm; kc += 64) {
        __syncthreads();
        {
            const u16* gx  = xh  + (size_t)(t0 + srow) * Dm + kc + sc16;
            const u16* gwq = WQb + (size_t)srow * Dm + kc + sc16;
            const u16* gwk = WKb + (size_t)srow * Dm + kc + sc16;
            const u16* gwv = WVb + (size_t)srow * Dm + kc + sc16;
            *(int4*)((char*)Xs  + sb0) = *(const int4*)gx;
            *(int4*)((char*)Xs  + sb1) = *(const int4*)(gx + 8);
            *(int4*)((char*)WsQ + sb0) = *(const int4*)gwq;
            *(int4*)((char*)WsQ + sb1) = *(const int4*)(gwq + 8);
            *(int4*)((char*)WsK + sb0) = *(const int4*)gwk;
            *(int4*)((char*)WsK + sb1) = *(const int4*)(gwk + 8);
            *(int4*)((char*)WsV + sb0) = *(const int4*)gwv;
            *(int4*)((char*)WsV + sb1) = *(const int4*)(gwv + 8);
        }
        __syncthreads();

        f16x8 ax[2];
        #pragma unroll
        for (int ks = 0; ks < 2; ++ks) {
            int row = 16 * w + b;
            int byt = (row * 128 + ks * 64 + a * 16) ^ ((row & 7) << 4);
            ax[ks] = *(const f16x8*)((const char*)Xs + byt);
        }
        __builtin_amdgcn_s_setprio(1);
        #pragma unroll
        for (int ct = 0; ct < 4; ++ct) {
            #pragma unroll
            for (int ks = 0; ks < 2; ++ks) {
                int row = 16 * ct + b;
                int byt = (row * 128 + ks * 64 + a * 16) ^ ((row & 7) << 4);
                f16x8 bq = *(const f16x8*)((const char*)WsQ + byt);
                f16x8 bk = *(const f16x8*)((const char*)WsK + byt);
                f16x8 bv = *(const f16x8*)((const char*)WsV + byt);
                aq[ct] = MFMAH(ax[ks], bq, aq[ct]);
                ak[ct] = MFMAH(ax[ks], bk, ak[ct]);
                av[ct] = MFMAH(ax[ks], bv, av[ct]);
            }
        }
        __builtin_amdgcn_s_setprio(0);
    }

    const size_t base = (size_t)h * T * DH;
    #pragma unroll
    for (int ct = 0; ct < 4; ++ct) {
        #pragma unroll
        for (int r = 0; r < 4; ++r) {
            int t = t0 + 16 * w + a * 4 + r;
            size_t off = base + (size_t)t * DH + 16 * ct + b;
            Qh[off] = f2h(aq[ct][r]);
            Kh[off] = f2h(ak[ct][r]);
            Vt[((size_t)h * DH + 16 * ct + b) * T + t] = f2h(av[ct][r]);
        }
    }
}

// ---------------------------------------------------------------------------
// fp16 MFMA flash attention, split-K (KS=2), swapped operands (r18-validated).
// 64x64 tile / 24.5 KB LDS is the proven optimum: dbuf (r15), setprio (r15),
// KS=4 (r19), KVBLK=128 (r26), QBLK=128 (r28) all regressed or neutral.
// ---------------------------------------------------------------------------
__global__ __launch_bounds__(256) void flash_mfma_split(
    const u16* __restrict__ Qh, const u16* __restrict__ Kh,
    const u16* __restrict__ Vt, const u16* __restrict__ AP,
    u16* __restrict__ Opart, float2* __restrict__ ml)
{
    __shared__ u16 Ks[4096];
    __shared__ u16 Vs[4096];
    __shared__ u16 Ps[4][1024];

    const int h = blockIdx.y, t0 = blockIdx.x * 64;
    const int split = blockIdx.z;
    const int s_begin = split * (T / KS), s_end = s_begin + T / KS;
    const int tid = threadIdx.x, w = tid >> 6, lane = tid & 63;
    const int b = lane & 15, a = lane >> 4;

    const size_t hTD = (size_t)h * T * DH;
    const int trow = t0 + 16 * w + b;

    const size_t qoff = hTD + (size_t)trow * DH + a * 8;
    f16x8 qf[2];
    qf[0] = *(const f16x8*)(Qh + qoff);
    qf[1] = *(const f16x8*)(Qh + qoff + 32);

    f32x4 oacc[4];
    float m_run = -INFINITY, l_run = 0.f;
    #pragma unroll
    for (int i = 0; i < 4; ++i) oacc[i] = (f32x4){0.f, 0.f, 0.f, 0.f};

    const int srow = tid >> 2, sc16 = (tid & 3) * 16;
    const int swz = (srow & 7) << 4;
    const int sb0 = (srow * 128 + sc16 * 2) ^ swz;
    const int sb1 = (srow * 128 + sc16 * 2 + 16) ^ swz;

    const u16* aprow = AP + (size_t)trow * T;

    for (int s0 = s_begin; s0 < s_end; s0 += 64) {
        __syncthreads();
        {
            const u16* gk = Kh + hTD + (size_t)(s0 + srow) * DH + sc16;
            const u16* gv = Vt + hTD + (size_t)srow * T + s0 + sc16;
            *(int4*)((char*)Ks + sb0) = *(const int4*)gk;
            *(int4*)((char*)Ks + sb1) = *(const int4*)(gk + 8);
            *(int4*)((char*)Vs + sb0) = *(const int4*)gv;
            *(int4*)((char*)Vs + sb1) = *(const int4*)(gv + 8);
        }
        __syncthreads();

        ushort4 ap4[4];
        #pragma unroll
        for (int ct = 0; ct < 4; ++ct)
            ap4[ct] = *(const ushort4*)(aprow + s0 + 16 * ct + 4 * a);

        f32x4 acc[4];
        #pragma unroll
        for (int ct = 0; ct < 4; ++ct) acc[ct] = (f32x4){0.f, 0.f, 0.f, 0.f};
        #pragma unroll
        for (int ct = 0; ct < 4; ++ct) {
            #pragma unroll
            for (int ks = 0; ks < 2; ++ks) {
                int row = 16 * ct + b;
                int byt = (row * 128 + ks * 64 + a * 16) ^ ((row & 7) << 4);
                f16x8 kf = *(const f16x8*)((const char*)Ks + byt);
                acc[ct] = MFMAH(kf, qf[ks], acc[ct]);   // swapped
            }
        }

        #pragma unroll
        for (int ct = 0; ct < 4; ++ct) {
            const u16* apu = (const u16*)&ap4[ct];
            #pragma unroll
            for (int r = 0; r < 4; ++r)
                acc[ct][r] += h2f(apu[r]);
        }

        float mx = acc[0][0];
        #pragma unroll
        for (int ct = 0; ct < 4; ++ct)
            #pragma unroll
            for (int r = 0; r < 4; ++r) mx = fmaxf(mx, acc[ct][r]);
        mx = fmaxf(mx, __shfl_xor(mx, 16));
        mx = fmaxf(mx, __shfl_xor(mx, 32));

        float mnew  = fmaxf(m_run, mx);
        float alpha = __expf(m_run - mnew);
        float rs = 0.f;
        #pragma unroll
        for (int ct = 0; ct < 4; ++ct) {
            #pragma unroll
            for (int r = 0; r < 4; ++r) {
                float p = __expf(acc[ct][r] - mnew);
                acc[ct][r] = p;
                rs += p;
            }
        }
        rs += __shfl_xor(rs, 16);
        rs += __shfl_xor(rs, 32);
        l_run = l_run * alpha + rs;
        m_run = mnew;
        #pragma unroll
        for (int dt = 0; dt < 4; ++dt) {
            oacc[dt][0] *= alpha; oacc[dt][1] *= alpha;
            oacc[dt][2] *= alpha; oacc[dt][3] *= alpha;
        }

        #pragma unroll
        for (int ct = 0; ct < 4; ++ct) {
            union { fp16x2 h[2]; int2 i2; } u;
            u.h[0] = __builtin_amdgcn_cvt_pkrtz(acc[ct][0], acc[ct][1]);
            u.h[1] = __builtin_amdgcn_cvt_pkrtz(acc[ct][2], acc[ct][3]);
            int byt = (b * 128 + ct * 32 + a * 8) ^ ((b & 7) << 4);
            *(int2*)((char*)Ps[w] + byt) = u.i2;
        }

        f16x8 pa[2];
        #pragma unroll
        for (int ks = 0; ks < 2; ++ks) {
            int byt = (b * 128 + ks * 64 + a * 16) ^ ((b & 7) << 4);
            pa[ks] = *(const f16x8*)((const char*)Ps[w] + byt);
        }
        #pragma unroll
        for (int dt = 0; dt < 4; ++dt) {
            #pragma unroll
            for (int ks = 0; ks < 2; ++ks) {
                int row = 16 * dt + b;
                int byt = (row * 128 + ks * 64 + a * 16) ^ ((row & 7) << 4);
                f16x8 vf = *(const f16x8*)((const char*)Vs + byt);
                oacc[dt] = MFMAH(vf, pa[ks], oacc[dt]);   // swapped
            }
        }
    }

    const size_t pbase = ((size_t)split * NH + h) * T;
    #pragma unroll
    for (int dt = 0; dt < 4; ++dt) {
        ushort4 ov;
        ov.x = f2h(oacc[dt][0]); ov.y = f2h(oacc[dt][1]);
        ov.z = f2h(oacc[dt][2]); ov.w = f2h(oacc[dt][3]);
        *(ushort4*)(Opart + (pbase + trow) * DH + 16 * dt + 4 * a) = ov;
    }
    if (a == 0) ml[pbase + trow] = make_float2(m_run, l_run);
}

// ---------------------------------------------------------------------------
// Combine KS split partials; stores (m*, 1/L) for head 15 softmax fusion.
// ---------------------------------------------------------------------------
__global__ __launch_bounds__(256) void flash_combine(
    const u16* __restrict__ Opart, const float2* __restrict__ ml,
    u16* __restrict__ Ych, float2* __restrict__ mlfinal)
{
    int idx = blockIdx.x * 256 + threadIdx.x;
    int h = idx >> 14;
    int rem = idx & 16383;
    int t = rem >> 3;
    int d8 = (rem & 7) * 8;

    float2 mls[KS];
    size_t rr[KS];
    float m = -INFINITY;
    #pragma unroll
    for (int s = 0; s < KS; ++s) {
        rr[s] = ((size_t)s * NH + h) * T + t;
        mls[s] = ml[rr[s]];
        m = fmaxf(m, mls[s].x);
    }
    float wgt[KS], L = 0.f;
    #pragma unroll
    for (int s = 0; s < KS; ++s) {
        wgt[s] = __expf(mls[s].x - m);
        L += wgt[s] * mls[s].y;
    }
    float inv = 1.f / L;
    if (h == NH - 1 && d8 == 0) mlfinal[t] = make_float2(m, inv);

    float o[8] = {};
    #pragma unroll
    for (int s = 0; s < KS; ++s) {
        union { u16 u[8]; int4 v; } ov;
        ov.v = *(const int4*)(Opart + rr[s] * DH + d8);
        float ws = wgt[s] * inv;
        #pragma unroll
        for (int j = 0; j < 8; ++j) o[j] += h2f(ov.u[j]) * ws;
    }
    union { u16 u[8]; int4 v; } yo;
    #pragma unroll
    for (int j = 0; j < 8; ++j) yo.u[j] = f2h(o[j]);
    *(int4*)(Ych + (size_t)t * Dm + h * DH + d8) = yo.v;
}

// ---------------------------------------------------------------------------
// tail: fused gemm_out (blocks [0,512)) + head-15 score map ([512,1536)).
// ---------------------------------------------------------------------------
__global__ __launch_bounds__(256) void tail_kernel(
    const u16* __restrict__ Qh, const u16* __restrict__ Kh,
    const u16* __restrict__ AP, const float2* __restrict__ mlf,
    const u16* __restrict__ Ych, const u16* __restrict__ Wb,
    float* __restrict__ S, float* __restrict__ y)
{
    __shared__ u16 lds[8192];
    const int blk = blockIdx.x, tid = threadIdx.x;
    const int w = tid >> 6, lane = tid & 63;
    const int b = lane & 15, a = lane >> 4;
    const int srow = tid >> 2, sc16 = (tid & 3) * 16;
    const int swz = (srow & 7) << 4;
    const int sb0 = (srow * 128 + sc16 * 2) ^ swz;
    const int sb1 = (srow * 128 + sc16 * 2 + 16) ^ swz;

    if (blk < 512) {
        // ---- gemm_out: y = Ych @ Wb^T ----
        u16* As = lds;
        u16* Bs = lds + 4096;
        const int n0 = (blk & 15) * 64, t0 = (blk >> 4) * 64;

        f32x4 acc[4];
        #pragma unroll
        for (int ct = 0; ct < 4; ++ct) acc[ct] = (f32x4){0.f, 0.f, 0.f, 0.f};

        for (int kc = 0; kc < Dm; kc += 64) {
            __syncthreads();
            {
                const u16* ga = Ych + (size_t)(t0 + srow) * Dm + kc + sc16;
                const u16* gb = Wb  + (size_t)(n0 + srow) * Dm + kc + sc16;
                *(int4*)((char*)As + sb0) = *(const int4*)ga;
                *(int4*)((char*)As + sb1) = *(const int4*)(ga + 8);
                *(int4*)((char*)Bs + sb0) = *(const int4*)gb;
                *(int4*)((char*)Bs + sb1) = *(const int4*)(gb + 8);
            }
            __syncthreads();

            f16x8 af[2];
            #pragma unroll
            for (int ks = 0; ks < 2; ++ks) {
                int row = 16 * w + b;
                int byt = (row * 128 + ks * 64 + a * 16) ^ ((row & 7) << 4);
                af[ks] = *(const f16x8*)((const char*)As + byt);
            }
            __builtin_amdgcn_s_setprio(1);
            #pragma unroll
            for (int ct = 0; ct < 4; ++ct) {
                #pragma unroll
                for (int ks = 0; ks < 2; ++ks) {
                    int row = 16 * ct + b;
                    int byt = (row * 128 + ks * 64 + a * 16) ^ ((row & 7) << 4);
                    f16x8 bw = *(const f16x8*)((const char*)Bs + byt);
                    acc[ct] = MFMAH(af[ks], bw, acc[ct]);
                }
            }
            __builtin_amdgcn_s_setprio(0);
        }

        #pragma unroll
        for (int r = 0; r < 4; ++r) {
            int t = t0 + 16 * w + a * 4 + r;
            #pragma unroll
            for (int ct = 0; ct < 4; ++ct)
                y[(size_t)t * Dm + n0 + 16 * ct + b] = acc[ct][r];
        }
    } else {
        // ---- head-15 score map with fused softmax (swapped operands) ----
        u16* Ks = lds;
        const int rel = blk - 512;
        const int s0 = (rel & 31) * 64, t0 = (rel >> 5) * 64;
        const int h = NH - 1;
        const size_t hTD = (size_t)h * T * DH;
        const int trow = t0 + 16 * w + b;

        {
            const u16* gk = Kh + hTD + (size_t)(s0 + srow) * DH + sc16;
            *(int4*)((char*)Ks + sb0) = *(const int4*)gk;
            *(int4*)((char*)Ks + sb1) = *(const int4*)(gk + 8);
        }

        const size_t qoff = hTD + (size_t)trow * DH + a * 8;
        f16x8 qf[2];
        qf[0] = *(const f16x8*)(Qh + qoff);
        qf[1] = *(const f16x8*)(Qh + qoff + 32);
        __syncthreads();

        ushort4 ap4[4];
        #pragma unroll
        for (int ct = 0; ct < 4; ++ct)
            ap4[ct] = *(const ushort4*)(AP + (size_t)trow * T + s0 + 16 * ct + 4 * a);
        float2 fml = mlf[trow];

        f32x4 acc[4];
        #pragma unroll
        for (int ct = 0; ct < 4; ++ct) acc[ct] = (f32x4){0.f, 0.f, 0.f, 0.f};
        #pragma unroll
        for (int ct = 0; ct < 4; ++ct) {
            #pragma unroll
            for (int ks = 0; ks < 2; ++ks) {
                int row = 16 * ct + b;
                int byt = (row * 128 + ks * 64 + a * 16) ^ ((row & 7) << 4);
                f16x8 kf = *(const f16x8*)((const char*)Ks + byt);
                acc[ct] = MFMAH(kf, qf[ks], acc[ct]);    // swapped
            }
        }

        #pragma unroll
        for (int ct = 0; ct < 4; ++ct) {
            const u16* apu = (const u16*)&ap4[ct];
            float4 o;
            o.x = __expf(acc[ct][0] + h2f(apu[0]) - fml.x) * fml.y;
            o.y = __expf(acc[ct][1] + h2f(apu[1]) - fml.x) * fml.y;
            o.z = __expf(acc[ct][2] + h2f(apu[2]) - fml.x) * fml.y;
            o.w = __expf(acc[ct][3] + h2f(apu[3]) - fml.x) * fml.y;
            *(float4*)(S + (size_t)trow * T + s0 + 16 * ct + 4 * a) = o;
        }
    }
}

// ---------------------------------------------------------------------------
extern "C" void kernel_launch(void* const* d_in, const int* in_sizes, int n_in,
                              void* d_out, int out_size, void* d_ws, size_t ws_size,
                              hipStream_t stream)
{
    const float* x    = (const float*)d_in[0];
    const float* Wq   = (const float*)d_in[1];
    const float* Wk   = (const float*)d_in[2];
    const float* Wv   = (const float*)d_in[3];
    const float* Wout = (const float*)d_in[4];

    float* out      = (float*)d_out;
    float* y_out    = out;
    float* attn_out = out + (long)T * Dm;     // written LAST -> usable scratch

    // ---- workspace layout (32.6 MB; 34.5 MB proven) ----
    char* ws = (char*)d_ws;
    const size_t MB = 1024 * 1024;
    u16* Qh = (u16*)ws;                                // 4 MB
    u16* Kh = (u16*)(ws + 4 * MB);                     // 4 MB
    u16* Vt = (u16*)(ws + 8 * MB);                     // 4 MB
    char* C = ws + 12 * MB;
    u16* xh    = (u16*)C;                              // 4 MB (dead after proj)
    u16* Ych   = (u16*)C;                              // aliases xh (phase 2)
    u16* Wtb   = (u16*)(C + 4 * MB);                   // 6 MB
    u16* Woutb = (u16*)(C + 10 * MB);                  // 2 MB
    u16* APt   = (u16*)(C + 12 * MB);                  // 8 MB ([t][s])
    float2* mlfinal = (float2*)(C + 20 * MB);          // 16 KB
    float2* mlbuf   = (float2*)(C + 20 * MB + 65536);  // 512 KB
    // split-K partial O in d_out attn region (overwritten by tail/score):
    u16* Opart = (u16*)attn_out;                       // KS x 4 MB = 8 MB
    (void)ws_size;

    // 1) fused prep: xconv + wtrans + wout_conv + AP table
    prep_kernel<<<dim3(12032), dim3(256), 0, stream>>>(
        x, Wq, Wk, Wv, Wout, xh, Wtb, Woutb, APt);

    // 2) fused QKV projection
    proj_mfma<<<dim3(T / 64, NH), dim3(256), 0, stream>>>(xh, Wtb, Qh, Kh, Vt);

    // 3) split-K flash attention
    flash_mfma_split<<<dim3(T / 64, NH, KS), dim3(256), 0, stream>>>(
        Qh, Kh, Vt, APt, Opart, mlbuf);

    // 4) combine partials -> Ych + (m*,1/L)
    flash_combine<<<dim3(NH * T * 8 / 256), dim3(256), 0, stream>>>(
        Opart, mlbuf, Ych, mlfinal);

    // 5) fused tail: output projection + head-15 attention map
    tail_kernel<<<dim3(1536), dim3(256), 0, stream>>>(
        Qh, Kh, APt, mlfinal, Ych, Woutb, attn_out, y_out);
}